// Round 7
// baseline (335.223 us; speedup 1.0000x reference)
//
#include <hip/hip_runtime.h>
#include <hip/hip_bf16.h>
#include <string.h>

typedef __hip_bfloat16 bf16;
typedef __attribute__((ext_vector_type(8))) short short8;
typedef __attribute__((ext_vector_type(4))) float f32x4;

#define Bsz 512
#define S3  512
#define Tsz 16
#define Cc  128
#define TT  15
#define EPSv 1e-5f

__device__ __forceinline__ float u2f(unsigned short u) {
    return __uint_as_float(((unsigned)u) << 16);
}
__device__ __forceinline__ float ulo(unsigned u) { return __uint_as_float(u << 16); }
__device__ __forceinline__ float uhi(unsigned u) { return __uint_as_float(u & 0xffff0000u); }
__device__ __forceinline__ unsigned short f2bu(float v) {
    bf16 h = __float2bfloat16(v);
    unsigned short u; memcpy(&u, &h, 2); return u;
}
// fast RNE bf16 (no NaN path — inputs finite)
__device__ __forceinline__ unsigned short bfr16(float a) {
    unsigned u = __float_as_uint(a);
    u = u + 0x7fffu + ((u >> 16) & 1u);
    return (unsigned short)(u >> 16);
}
__device__ __forceinline__ unsigned fpack2(float a, float b) {
    unsigned ua = __float_as_uint(a), ub = __float_as_uint(b);
    ua = ua + 0x7fffu + ((ua >> 16) & 1u);
    ub = ub + 0x7fffu + ((ub >> 16) & 1u);
    return (ua >> 16) | (ub & 0xffff0000u);
}
__device__ __forceinline__ float dot4(float4 a, float4 b) {
    return a.x*b.x + a.y*b.y + a.z*b.z + a.w*b.w;
}

// ---------------------------------------------------------------------------
// k_tpack: src (NR x NK) row-major fp32 -> float4-packed k-major (Wl for base)
// ---------------------------------------------------------------------------
__global__ __launch_bounds__(256) void k_tpack(const float* __restrict__ src,
                                               float* __restrict__ dst,
                                               int NR, int NK)
{
    __shared__ float tile[32][33];
    int k0 = blockIdx.x * 32, r0 = blockIdx.y * 32;
    int lr = threadIdx.x >> 5, lk = threadIdx.x & 31;
    for (int i = lr; i < 32; i += 8)
        tile[i][lk] = src[(size_t)(r0 + i) * NK + k0 + lk];
    __syncthreads();
    int c = threadIdx.x & 31, k4 = threadIdx.x >> 5;
    float4 v;
    v.x = tile[c][k4 * 4 + 0]; v.y = tile[c][k4 * 4 + 1];
    v.z = tile[c][k4 * 4 + 2]; v.w = tile[c][k4 * 4 + 3];
    ((float4*)dst)[(size_t)(k0 / 4 + k4) * NR + r0 + c] = v;
}

// ---------------------------------------------------------------------------
// k_cvt: fp32 -> bf16 elementwise
// ---------------------------------------------------------------------------
__global__ __launch_bounds__(256) void k_cvt(const float* __restrict__ src,
                                             ushort* __restrict__ dst, int n4)
{
    int i = blockIdx.x * 256 + threadIdx.x;
    if (i < n4) {
        float4 v = ((const float4*)src)[i];
        ushort4 o;
        o.x = f2bu(v.x); o.y = f2bu(v.y); o.z = f2bu(v.z); o.w = f2bu(v.w);
        ((ushort4*)dst)[i] = o;
    }
}

// ---------------------------------------------------------------------------
// k_dwall: d = Wr - inv*Wl -> bf16 in MFMA-fragment-major layout.
// dbuf[((b*3+l)*32 + (t*4+ks))*512 + lane*8 + j]
// ---------------------------------------------------------------------------
__global__ __launch_bounds__(256) void k_dwall(
    const int* __restrict__ xx, const float* __restrict__ Wl,
    const float* __restrict__ Wr, ushort* __restrict__ dbuf)
{
    __shared__ float pc[4];
    __shared__ float winv;
    int b = blockIdx.x, l = blockIdx.y, tid = threadIdx.x;
    const int* x0 = xx + (size_t)b * Tsz * S3;
    int c = (x0[tid] != 0) + (x0[tid + 256] != 0);
    for (int off = 32; off; off >>= 1) c += __shfl_xor(c, off, 64);
    if ((tid & 63) == 0) pc[tid >> 6] = (float)c;
    __syncthreads();
    if (tid == 0) {
        float n = pc[0] + pc[1] + pc[2] + pc[3];
        winv = (n > 1.f) ? 1.f / (n - 1.f) : 0.f;
    }
    __syncthreads();
    float inv = winv;
    const float* wl = Wl + l * 16384;
    const float* wr = Wr + l * 16384;
    ushort* dst = dbuf + (size_t)(b * 3 + l) * 32 * 512;
    for (int item = tid; item < 2048; item += 256) {
        int f = item >> 6, lane = item & 63;
        int t = f >> 2, ks = f & 3, ml = lane & 15, q = lane >> 4;
        int n = t * 16 + ml, kb = ks * 32 + q * 8;
        const float4* wlr = (const float4*)(wl + n * 128 + kb);
        const float4* wrr = (const float4*)(wr + n * 128 + kb);
        float4 a0 = wlr[0], a1 = wlr[1];
        float4 r0 = wrr[0], r1 = wrr[1];
        ushort4 o0, o1;
        o0.x = f2bu(r0.x - inv * a0.x); o0.y = f2bu(r0.y - inv * a0.y);
        o0.z = f2bu(r0.z - inv * a0.z); o0.w = f2bu(r0.w - inv * a0.w);
        o1.x = f2bu(r1.x - inv * a1.x); o1.y = f2bu(r1.y - inv * a1.y);
        o1.z = f2bu(r1.z - inv * a1.z); o1.w = f2bu(r1.w - inv * a1.w);
        ushort* dp = dst + (size_t)f * 512 + lane * 8;
        *(ushort4*)dp = o0;
        *(ushort4*)(dp + 4) = o1;
    }
}

// ---------------------------------------------------------------------------
// k_torso: fused init + 3 GNN layers + pool. 1024 threads (16 waves);
// wave wv owns nodes [wv*32, wv*32+32). Epilogue uses in-place acc (no h[])
// to stay under the 64 arch-VGPR budget (16 waves -> 128 total regs/thread).
// ---------------------------------------------------------------------------
__global__ __launch_bounds__(1024) void k_torso(
    const int* __restrict__ xx, const float* __restrict__ ss,
    const float* __restrict__ Win, const float* __restrict__ b_in,
    const ushort* __restrict__ dbuf,
    const float4* __restrict__ WlP, const float* __restrict__ blv,
    const float* __restrict__ lng, const float* __restrict__ lnb,
    float* __restrict__ out)
{
    __shared__ ushort X[512 * 136];
    __shared__ float  mC[512];
    __shared__ float  sred[16 * 128];
    __shared__ float  ssc[128];
    __shared__ float  sbase[128];
    __shared__ float  gln[128], bln[128];
    __shared__ float  scnt[16];
    __shared__ float  invS;

    int b = blockIdx.x, tid = threadIdx.x;
    int wv = tid >> 6, lane = tid & 63;
    int ml = lane & 15, quad = lane >> 4;

    // ================= init =================
    {
        int g = wv, cp = lane;
        int co0 = 2 * cp, co1 = 2 * cp + 1;
        const int* x0 = xx + (size_t)b * Tsz * S3;
        float f4c = ss[b] * (1.0f / 8.0f);
        float a0 = Win[co0*5+0], a1 = Win[co0*5+1], a2 = Win[co0*5+2], a3 = Win[co0*5+3];
        float c0 = Win[co1*5+0], c1 = Win[co1*5+1], c2 = Win[co1*5+2], c3 = Win[co1*5+3];
        float ba = b_in[co0] + f4c * Win[co0*5+4];
        float bc = b_in[co1] + f4c * Win[co1*5+4];
        float sp0 = 0.f, sp1 = 0.f; int cnt = 0;
        for (int node = g; node < S3; node += 16) {
            int f0 = x0[node];
            float m = (f0 != 0) ? 1.f : 0.f;
            float ci = (float)(node >> 6) * (1.f / 7.f);
            float cj = (float)((node >> 3) & 7) * (1.f / 7.f);
            float ck = (float)(node & 7) * (1.f / 7.f);
            float ft = (float)f0 * 0.5f;
            float v0 = ba + ci * a0 + cj * a1 + ck * a2 + ft * a3;
            float v1 = bc + ci * c0 + cj * c1 + ck * c2 + ft * c3;
            ((unsigned*)(X + node * 136))[cp] = fpack2(v0, v1);
            sp0 += v0 * m; sp1 += v1 * m;
            cnt += (f0 != 0);
            if (cp == 0) mC[node] = m;
        }
        sred[g * 128 + co0] = sp0;
        sred[g * 128 + co1] = sp1;
        if (cp == 0) scnt[g] = (float)cnt;
    }
    if (tid < 128) { gln[tid] = lng[tid]; bln[tid] = lnb[tid]; }
    __syncthreads();
    if (tid == 0) {
        float n = 0.f;
#pragma unroll
        for (int g = 0; g < 16; g++) n += scnt[g];
        invS = (n > 1.f) ? 1.f / (n - 1.f) : 0.f;
    }
    __syncthreads();
    if (tid < 128) {
        float s = 0.f;
#pragma unroll
        for (int g = 0; g < 16; g++) s += sred[g * 128 + tid];
        ssc[tid] = s * invS;
    }
    __syncthreads();
    if (tid < 128) {
        float a = blv[tid];
        for (int k4 = 0; k4 < 32; k4++)
            a += dot4(*(const float4*)(ssc + k4 * 4), WlP[k4 * 384 + tid]);
        sbase[tid] = a;
    }
    __syncthreads();

    // ================= 3 SAGE layers =================
    for (int l = 0; l < 3; l++) {
        f32x4 acc[2][8];
#pragma unroll
        for (int m = 0; m < 2; m++)
#pragma unroll
            for (int t = 0; t < 8; t++) acc[m][t] = (f32x4){0.f, 0.f, 0.f, 0.f};

        const ushort* dL = dbuf + (size_t)(b * 3 + l) * 32 * 512;
#pragma unroll
        for (int ks = 0; ks < 4; ks++) {
            short8 bfr[8];
#pragma unroll
            for (int t = 0; t < 8; t++)
                bfr[t] = *(const short8*)(dL + (size_t)(t * 4 + ks) * 512 + lane * 8);
#pragma unroll
            for (int m = 0; m < 2; m++) {
                short8 a = *(const short8*)(X + (wv * 32 + m * 16 + ml) * 136 + quad * 8 + ks * 32);
#pragma unroll
                for (int t = 0; t < 8; t++)
                    acc[m][t] = __builtin_amdgcn_mfma_f32_16x16x32_bf16(a, bfr[t], acc[m][t], 0, 0, 0);
            }
        }

        // epilogue: relu+base in-place into acc -> LN -> bf16 into X
        float bse[8], gg[8], be[8];
#pragma unroll
        for (int t = 0; t < 8; t++) {
            bse[t] = sbase[t * 16 + ml];
            gg[t]  = gln[t * 16 + ml];
            be[t]  = bln[t * 16 + ml];
        }
        float sp[8];
#pragma unroll
        for (int t = 0; t < 8; t++) sp[t] = 0.f;
        bool last = (l == 2);

#pragma unroll
        for (int m = 0; m < 2; m++) {
#pragma unroll
            for (int r = 0; r < 4; r++) {
                int row = wv * 32 + m * 16 + quad * 4 + r;
                float s = 0.f, q = 0.f;
#pragma unroll
                for (int t = 0; t < 8; t++) {
                    float v = fmaxf(acc[m][t][r] + bse[t], 0.f);
                    acc[m][t][r] = v;
                    s += v; q += v * v;
                }
#pragma unroll
                for (int off = 1; off <= 8; off <<= 1) {
                    s += __shfl_xor(s, off, 64);
                    q += __shfl_xor(q, off, 64);
                }
                float mu = s * (1.f / 128.f);
                float rs = rsqrtf(q * (1.f / 128.f) - mu * mu + EPSv);
                float mrow = mC[row];
#pragma unroll
                for (int t = 0; t < 8; t++) {
                    float y = (acc[m][t][r] - mu) * rs * gg[t] + be[t];
                    if (last) y *= mrow;
                    else sp[t] += y * mrow;
                    X[row * 136 + t * 16 + ml] = bfr16(y);
                }
            }
        }

        if (!last) {
#pragma unroll
            for (int t = 0; t < 8; t++) {
                sp[t] += __shfl_xor(sp[t], 16, 64);
                sp[t] += __shfl_xor(sp[t], 32, 64);
            }
            if (quad == 0) {
#pragma unroll
                for (int t = 0; t < 8; t++) sred[wv * 128 + t * 16 + ml] = sp[t];
            }
            __syncthreads();
            if (tid < 128) {
                float s = 0.f;
#pragma unroll
                for (int g = 0; g < 16; g++) s += sred[g * 128 + tid];
                ssc[tid] = s * invS;
            }
            __syncthreads();
            if (tid < 128) {
                float a = blv[(l + 1) * 128 + tid];
                for (int k4 = 0; k4 < 32; k4++)
                    a += dot4(*(const float4*)(ssc + k4 * 4), WlP[k4 * 384 + (l + 1) * 128 + tid]);
                sbase[tid] = a;
            }
            __syncthreads();
        }
    }
    __syncthreads();

    // ================= pool: slice means, 4-channel vectorized =================
    if (tid < 768) {
        int c4 = tid & 31, p = tid >> 5;
        int axis = p >> 3, idx = p & 7;
        float4 sum = {0.f, 0.f, 0.f, 0.f};
        for (int t = 0; t < 64; t++) {
            int node;
            if (axis == 0)      node = idx * 64 + t;
            else if (axis == 1) node = (t >> 3) * 64 + idx * 8 + (t & 7);
            else                node = t * 8 + idx;
            uint2 pk = *(const uint2*)(X + node * 136 + c4 * 4);
            sum.x += ulo(pk.x);
            sum.y += uhi(pk.x);
            sum.z += ulo(pk.y);
            sum.w += uhi(pk.y);
        }
        float4 o;
        o.x = sum.x * (1.f / 64.f); o.y = sum.y * (1.f / 64.f);
        o.z = sum.z * (1.f / 64.f); o.w = sum.w * (1.f / 64.f);
        *(float4*)(out + (size_t)b * 26 * Cc + p * Cc + c4 * 4) = o;
    }
}

// ---------------------------------------------------------------------------
// k_tf3: transformer, bf16 MFMA GEMMs; q/k/v stored bf16 -> ~50 KB LDS
// -> 3 blocks/CU.
// ---------------------------------------------------------------------------
__global__ __launch_bounds__(256) void k_tf3(
    const int* __restrict__ xx, const float* __restrict__ ss,
    const ushort* __restrict__ WactB, const float* __restrict__ bact,
    const ushort* __restrict__ WqkvB, const float* __restrict__ bqkv,
    const ushort* __restrict__ WoB, const float* __restrict__ bo,
    const float* __restrict__ ln1g, const float* __restrict__ ln1b,
    const float* __restrict__ ln2g, const float* __restrict__ ln2b,
    const ushort* __restrict__ W1B, const float* __restrict__ b1v,
    const ushort* __restrict__ W2B, const float* __restrict__ b2v,
    const float* __restrict__ Wsc, const float* __restrict__ bsc,
    float* __restrict__ out)
{
    __shared__ float  As[TT * 132];     // fp32 residual stream
    __shared__ ushort Qs[16 * 392];     // bf16 q|k|v
    __shared__ ushort Ab[16 * 136];     // bf16 LN output (A operand)
    __shared__ ushort Hs[16 * 136];     // bf16 attn output (A operand)
    __shared__ ushort Fs[16 * 520];     // bf16 K=512 A operand
    __shared__ float  Att[60 * 16];
    __shared__ float  mu_s[TT], rs_s[TT];

    int b = blockIdx.x, tid = threadIdx.x;
    int wv = tid >> 6, lane = tid & 63;
    int ml = lane & 15, quad = lane >> 4;

    const int* xa = xx + (size_t)b * Tsz * S3 + S3;
    for (int f = tid; f < TT * 512; f += 256) {
        int t = f >> 9, s = f & 511;
        Fs[t * 520 + s] = bfr16((float)xa[t * 512 + s]);
    }
    __syncthreads();

    {
        f32x4 acc[2];
#pragma unroll
        for (int i = 0; i < 2; i++) acc[i] = (f32x4){0.f, 0.f, 0.f, 0.f};
        const ushort* ar = Fs + ml * 520 + quad * 8;
        for (int ks = 0; ks < 16; ks++) {
            short8 a = *(const short8*)(ar + ks * 32);
#pragma unroll
            for (int i = 0; i < 2; i++) {
                int n0 = (wv * 2 + i) * 16;
                short8 bfr = *(const short8*)(WactB + (size_t)(n0 + ml) * 512 + quad * 8 + ks * 32);
                acc[i] = __builtin_amdgcn_mfma_f32_16x16x32_bf16(a, bfr, acc[i], 0, 0, 0);
            }
        }
#pragma unroll
        for (int i = 0; i < 2; i++) {
            int col = (wv * 2 + i) * 16 + ml;
            float bb = bact[col];
#pragma unroll
            for (int r = 0; r < 4; r++) {
                int row = quad * 4 + r;
                if (row < TT) As[row * 132 + col] = acc[i][r] + bb;
            }
        }
    }
    __syncthreads();

    for (int l = 0; l < 2; l++) {
        const float* bq  = bqkv + l * 384;
        const float* bol = bo + l * 128;
        const float* g1  = ln1g + l * 128; const float* be1 = ln1b + l * 128;
        const float* g2  = ln2g + l * 128; const float* be2 = ln2b + l * 128;
        const float* b1l = b1v + l * 512;  const float* b2l = b2v + l * 128;

        // LN1
        for (int r = wv; r < TT; r += 4) {
            float2 v = *(const float2*)(As + r * 132 + lane * 2);
            float s = v.x + v.y, q = v.x * v.x + v.y * v.y;
            for (int off = 32; off; off >>= 1) {
                s += __shfl_xor(s, off, 64);
                q += __shfl_xor(q, off, 64);
            }
            if (lane == 0) {
                float mu = s * (1.f / 128.f);
                mu_s[r] = mu;
                rs_s[r] = rsqrtf(q * (1.f / 128.f) - mu * mu + EPSv);
            }
        }
        __syncthreads();
        for (int f = tid; f < TT * 64; f += 256) {
            int t = f >> 6, cp = f & 63;
            float mu = mu_s[t], rs = rs_s[t];
            float x0 = (As[t * 132 + 2 * cp]     - mu) * rs * g1[2 * cp]     + be1[2 * cp];
            float x1 = (As[t * 132 + 2 * cp + 1] - mu) * rs * g1[2 * cp + 1] + be1[2 * cp + 1];
            ((unsigned*)(Ab + t * 136))[cp] = fpack2(x0, x1);
        }
        __syncthreads();

        // qkv (K=128, N=384) -> Qs bf16
        {
            short8 a[4];
            const ushort* ar = Ab + ml * 136 + quad * 8;
#pragma unroll
            for (int ks = 0; ks < 4; ks++) a[ks] = *(const short8*)(ar + ks * 32);
#pragma unroll
            for (int i = 0; i < 6; i++) {
                int n0 = (wv * 6 + i) * 16;
                f32x4 acc = (f32x4){0.f, 0.f, 0.f, 0.f};
                const ushort* wb = WqkvB + (size_t)(l * 384 + n0 + ml) * 128 + quad * 8;
#pragma unroll
                for (int ks = 0; ks < 4; ks++) {
                    short8 bfr = *(const short8*)(wb + ks * 32);
                    acc = __builtin_amdgcn_mfma_f32_16x16x32_bf16(a[ks], bfr, acc, 0, 0, 0);
                }
                int col = n0 + ml;
                float bb = bq[col];
#pragma unroll
                for (int r = 0; r < 4; r++) {
                    int row = quad * 4 + r;
                    if (row < TT) Qs[row * 392 + col] = bfr16(acc[r] + bb);
                }
            }
        }
        __syncthreads();

        // attention scores + softmax (60 threads, fp32 accum over bf16 q/k)
        if (tid < 60) {
            int h = tid / 15, tq = tid % 15;
            const ushort* qp = Qs + tq * 392 + h * 32;
            float sc[TT];
            float mx = -1e30f;
#pragma unroll
            for (int tk = 0; tk < TT; tk++) {
                const ushort* kp = Qs + tk * 392 + 128 + h * 32;
                float d = 0.f;
#pragma unroll
                for (int u = 0; u < 32; u += 4) {
                    uint2 qa = *(const uint2*)(qp + u);
                    uint2 ka = *(const uint2*)(kp + u);
                    d += ulo(qa.x) * ulo(ka.x) + uhi(qa.x) * uhi(ka.x)
                       + ulo(qa.y) * ulo(ka.y) + uhi(qa.y) * uhi(ka.y);
                }
                d *= 0.17677669529663689f;
                sc[tk] = d; mx = fmaxf(mx, d);
            }
            float sum = 0.f;
#pragma unroll
            for (int tk = 0; tk < TT; tk++) { float e = __expf(sc[tk] - mx); sc[tk] = e; sum += e; }
            float r = 1.f / sum;
#pragma unroll
            for (int tk = 0; tk < TT; tk++) Att[tid * 16 + tk] = sc[tk] * r;
        }
        __syncthreads();

        // o = att @ v -> Hs (bf16); v read bf16-packed
        for (int f = tid; f < TT * 64; f += 256) {
            int t = f >> 6, cp = f & 63;
            int h = cp >> 4;                    // head of channel pair (2cp)>>5
            const float* ap = Att + (h * 15 + t) * 16;
            const ushort* vp = Qs + 256 + 2 * cp;
            float a0 = 0.f, a1 = 0.f;
#pragma unroll
            for (int tk = 0; tk < TT; tk++) {
                float w = ap[tk];
                unsigned pk = *(const unsigned*)(vp + tk * 392);
                a0 += w * ulo(pk);
                a1 += w * uhi(pk);
            }
            ((unsigned*)(Hs + t * 136))[cp] = fpack2(a0, a1);
        }
        __syncthreads();

        // proj + residual
        {
            short8 a[4];
            const ushort* ar = Hs + ml * 136 + quad * 8;
#pragma unroll
            for (int ks = 0; ks < 4; ks++) a[ks] = *(const short8*)(ar + ks * 32);
#pragma unroll
            for (int i = 0; i < 2; i++) {
                int n0 = (wv * 2 + i) * 16;
                f32x4 acc = (f32x4){0.f, 0.f, 0.f, 0.f};
                const ushort* wb = WoB + (size_t)(l * 128 + n0 + ml) * 128 + quad * 8;
#pragma unroll
                for (int ks = 0; ks < 4; ks++) {
                    short8 bfr = *(const short8*)(wb + ks * 32);
                    acc = __builtin_amdgcn_mfma_f32_16x16x32_bf16(a[ks], bfr, acc, 0, 0, 0);
                }
                int col = n0 + ml;
                float bb = bol[col];
#pragma unroll
                for (int r = 0; r < 4; r++) {
                    int row = quad * 4 + r;
                    if (row < TT) As[row * 132 + col] += acc[r] + bb;
                }
            }
        }
        __syncthreads();

        // LN2
        for (int r = wv; r < TT; r += 4) {
            float2 v = *(const float2*)(As + r * 132 + lane * 2);
            float s = v.x + v.y, q = v.x * v.x + v.y * v.y;
            for (int off = 32; off; off >>= 1) {
                s += __shfl_xor(s, off, 64);
                q += __shfl_xor(q, off, 64);
            }
            if (lane == 0) {
                float mu = s * (1.f / 128.f);
                mu_s[r] = mu;
                rs_s[r] = rsqrtf(q * (1.f / 128.f) - mu * mu + EPSv);
            }
        }
        __syncthreads();
        for (int f = tid; f < TT * 64; f += 256) {
            int t = f >> 6, cp = f & 63;
            float mu = mu_s[t], rs = rs_s[t];
            float x0 = (As[t * 132 + 2 * cp]     - mu) * rs * g2[2 * cp]     + be2[2 * cp];
            float x1 = (As[t * 132 + 2 * cp + 1] - mu) * rs * g2[2 * cp + 1] + be2[2 * cp + 1];
            ((unsigned*)(Ab + t * 136))[cp] = fpack2(x0, x1);
        }
        __syncthreads();

        // ff1 (K=128, N=512)
        {
            short8 a[4];
            const ushort* ar = Ab + ml * 136 + quad * 8;
#pragma unroll
            for (int ks = 0; ks < 4; ks++) a[ks] = *(const short8*)(ar + ks * 32);
#pragma unroll
            for (int i = 0; i < 8; i++) {
                int n0 = (wv * 8 + i) * 16;
                f32x4 acc = (f32x4){0.f, 0.f, 0.f, 0.f};
                const ushort* wb = W1B + (size_t)(l * 512 + n0 + ml) * 128 + quad * 8;
#pragma unroll
                for (int ks = 0; ks < 4; ks++) {
                    short8 bfr = *(const short8*)(wb + ks * 32);
                    acc = __builtin_amdgcn_mfma_f32_16x16x32_bf16(a[ks], bfr, acc, 0, 0, 0);
                }
                int col = n0 + ml;
                float bb = b1l[col];
#pragma unroll
                for (int r = 0; r < 4; r++) {
                    int row = quad * 4 + r;
                    if (row < TT) Fs[row * 520 + col] = bfr16(fmaxf(acc[r] + bb, 0.f));
                }
            }
        }
        __syncthreads();

        // ff2 + residual (K=512, N=128)
        {
            f32x4 acc[2];
#pragma unroll
            for (int i = 0; i < 2; i++) acc[i] = (f32x4){0.f, 0.f, 0.f, 0.f};
            const ushort* ar = Fs + ml * 520 + quad * 8;
            for (int ks = 0; ks < 16; ks++) {
                short8 a = *(const short8*)(ar + ks * 32);
#pragma unroll
                for (int i = 0; i < 2; i++) {
                    int n0 = (wv * 2 + i) * 16;
                    short8 bfr = *(const short8*)(W2B + (size_t)(l * 128 + n0 + ml) * 512 + quad * 8 + ks * 32);
                    acc[i] = __builtin_amdgcn_mfma_f32_16x16x32_bf16(a, bfr, acc[i], 0, 0, 0);
                }
            }
#pragma unroll
            for (int i = 0; i < 2; i++) {
                int col = (wv * 2 + i) * 16 + ml;
                float bb = b2l[col];
#pragma unroll
                for (int r = 0; r < 4; r++) {
                    int row = quad * 4 + r;
                    if (row < TT) As[row * 132 + col] += acc[i][r] + bb;
                }
            }
        }
        __syncthreads();
    }

    if (tid < 128) {
        float s = 0.f;
#pragma unroll
        for (int t = 0; t < TT; t++) s += As[t * 132 + tid];
        out[(size_t)b * 26 * Cc + 24 * Cc + tid] = s * (1.f / 15.f);
    } else if (tid < 256) {
        int co = tid - 128;
        float v = ss[b] * Wsc[co] + bsc[co];
        out[(size_t)b * 26 * Cc + 25 * Cc + co] = fmaxf(v, 0.f);
    }
}

// ---------------------------------------------------------------------------
extern "C" void kernel_launch(void* const* d_in, const int* in_sizes, int n_in,
                              void* d_out, int out_size, void* d_ws, size_t ws_size,
                              hipStream_t stream)
{
    (void)in_sizes; (void)n_in; (void)out_size; (void)ws_size;
    const int*   xx   = (const int*)d_in[0];
    const float* ss   = (const float*)d_in[1];
    const float* Win  = (const float*)d_in[2];
    const float* b_in = (const float*)d_in[3];
    const float* Wl   = (const float*)d_in[4];
    const float* bl   = (const float*)d_in[5];
    const float* Wr   = (const float*)d_in[6];
    const float* lng  = (const float*)d_in[7];
    const float* lnb  = (const float*)d_in[8];
    const float* Wqkv = (const float*)d_in[9];
    const float* bqkv = (const float*)d_in[10];
    const float* Wo   = (const float*)d_in[11];
    const float* bo   = (const float*)d_in[12];
    const float* ln1g = (const float*)d_in[13];
    const float* ln1b = (const float*)d_in[14];
    const float* ln2g = (const float*)d_in[15];
    const float* ln2b = (const float*)d_in[16];
    const float* W1   = (const float*)d_in[17];
    const float* b1   = (const float*)d_in[18];
    const float* W2   = (const float*)d_in[19];
    const float* b2   = (const float*)d_in[20];
    const float* Wact = (const float*)d_in[21];
    const float* bact = (const float*)d_in[22];
    const float* Wsc  = (const float*)d_in[23];
    const float* bsc  = (const float*)d_in[24];
    float* out = (float*)d_out;

    char* ws = (char*)d_ws;
    size_t off = 0;
    float* WlT  = (float*)(ws + off); off += 384 * 128 * 4;
    ushort* dbuf  = (ushort*)(ws + off); off += (size_t)Bsz * 3 * 32 * 512 * 2;
    ushort* WactB = (ushort*)(ws + off); off += 128 * 512 * 2;
    ushort* WqkvB = (ushort*)(ws + off); off += 768 * 128 * 2;
    ushort* WoB   = (ushort*)(ws + off); off += 256 * 128 * 2;
    ushort* W1B   = (ushort*)(ws + off); off += 1024 * 128 * 2;
    ushort* W2B   = (ushort*)(ws + off); off += 256 * 512 * 2;

    k_tpack<<<dim3(4, 12), 256, 0, stream>>>(Wl, WlT, 384, 128);
    k_cvt<<<(128 * 512 / 4 + 255) / 256, 256, 0, stream>>>(Wact, WactB, 128 * 512 / 4);
    k_cvt<<<(768 * 128 / 4 + 255) / 256, 256, 0, stream>>>(Wqkv, WqkvB, 768 * 128 / 4);
    k_cvt<<<(256 * 128 / 4 + 255) / 256, 256, 0, stream>>>(Wo,   WoB,   256 * 128 / 4);
    k_cvt<<<(1024 * 128 / 4 + 255) / 256, 256, 0, stream>>>(W1,  W1B,  1024 * 128 / 4);
    k_cvt<<<(256 * 512 / 4 + 255) / 256, 256, 0, stream>>>(W2,   W2B,   256 * 512 / 4);

    k_dwall<<<dim3(Bsz, 3), 256, 0, stream>>>(xx, Wl, Wr, dbuf);

    k_torso<<<Bsz, 1024, 0, stream>>>(xx, ss, Win, b_in, dbuf,
                                      (const float4*)WlT, bl, lng, lnb, out);

    k_tf3<<<Bsz, 256, 0, stream>>>(xx, ss,
                                   WactB, bact, WqkvB, bqkv, WoB, bo,
                                   ln1g, ln1b, ln2g, ln2b,
                                   W1B, b1, W2B, b2,
                                   Wsc, bsc, out);
}

// Round 8
// 316.380 us; speedup vs baseline: 1.0596x; 1.0596x over previous
//
#include <hip/hip_runtime.h>
#include <hip/hip_bf16.h>
#include <string.h>

typedef __hip_bfloat16 bf16;
typedef __attribute__((ext_vector_type(8))) short short8;
typedef __attribute__((ext_vector_type(4))) float f32x4;

#define Bsz 512
#define S3  512
#define Tsz 16
#define Cc  128
#define TT  15
#define EPSv 1e-5f

__device__ __forceinline__ float u2f(unsigned short u) {
    return __uint_as_float(((unsigned)u) << 16);
}
__device__ __forceinline__ float ulo(unsigned u) { return __uint_as_float(u << 16); }
__device__ __forceinline__ float uhi(unsigned u) { return __uint_as_float(u & 0xffff0000u); }
__device__ __forceinline__ unsigned short f2bu(float v) {
    bf16 h = __float2bfloat16(v);
    unsigned short u; memcpy(&u, &h, 2); return u;
}
// fast RNE bf16 (no NaN path — inputs finite)
__device__ __forceinline__ unsigned short bfr16(float a) {
    unsigned u = __float_as_uint(a);
    u = u + 0x7fffu + ((u >> 16) & 1u);
    return (unsigned short)(u >> 16);
}
__device__ __forceinline__ unsigned fpack2(float a, float b) {
    unsigned ua = __float_as_uint(a), ub = __float_as_uint(b);
    ua = ua + 0x7fffu + ((ua >> 16) & 1u);
    ub = ub + 0x7fffu + ((ub >> 16) & 1u);
    return (ua >> 16) | (ub & 0xffff0000u);
}
__device__ __forceinline__ float dot4(float4 a, float4 b) {
    return a.x*b.x + a.y*b.y + a.z*b.z + a.w*b.w;
}

// ---------------------------------------------------------------------------
// k_tpack: src (NR x NK) row-major fp32 -> float4-packed k-major (Wl for base)
// ---------------------------------------------------------------------------
__global__ __launch_bounds__(256) void k_tpack(const float* __restrict__ src,
                                               float* __restrict__ dst,
                                               int NR, int NK)
{
    __shared__ float tile[32][33];
    int k0 = blockIdx.x * 32, r0 = blockIdx.y * 32;
    int lr = threadIdx.x >> 5, lk = threadIdx.x & 31;
    for (int i = lr; i < 32; i += 8)
        tile[i][lk] = src[(size_t)(r0 + i) * NK + k0 + lk];
    __syncthreads();
    int c = threadIdx.x & 31, k4 = threadIdx.x >> 5;
    float4 v;
    v.x = tile[c][k4 * 4 + 0]; v.y = tile[c][k4 * 4 + 1];
    v.z = tile[c][k4 * 4 + 2]; v.w = tile[c][k4 * 4 + 3];
    ((float4*)dst)[(size_t)(k0 / 4 + k4) * NR + r0 + c] = v;
}

// ---------------------------------------------------------------------------
// k_cvt5: all 5 transformer weights fp32 -> bf16 in one launch.
// dst regions are contiguous: Wact(16384 f4) | Wqkv(24576) | Wo(8192) |
// W1(32768) | W2(32768) -> 114688 float4 groups total, 448 blocks.
// ---------------------------------------------------------------------------
__global__ __launch_bounds__(256) void k_cvt5(
    const float* __restrict__ s0, const float* __restrict__ s1,
    const float* __restrict__ s2, const float* __restrict__ s3,
    const float* __restrict__ s4, ushort* __restrict__ dst)
{
    int i = blockIdx.x * 256 + threadIdx.x;
    if (i >= 114688) return;
    const float* src; int rel;
    if (i < 16384)      { src = s0; rel = i; }
    else if (i < 40960) { src = s1; rel = i - 16384; }
    else if (i < 49152) { src = s2; rel = i - 40960; }
    else if (i < 81920) { src = s3; rel = i - 49152; }
    else                { src = s4; rel = i - 81920; }
    float4 v = ((const float4*)src)[rel];
    ushort4 o;
    o.x = f2bu(v.x); o.y = f2bu(v.y); o.z = f2bu(v.z); o.w = f2bu(v.w);
    ((ushort4*)dst)[i] = o;
}

// ---------------------------------------------------------------------------
// k_dwall: d = Wr - inv*Wl -> bf16 in MFMA-fragment-major layout.
// dbuf[((b*3+l)*32 + (t*4+ks))*512 + lane*8 + j]
// ---------------------------------------------------------------------------
__global__ __launch_bounds__(256) void k_dwall(
    const int* __restrict__ xx, const float* __restrict__ Wl,
    const float* __restrict__ Wr, ushort* __restrict__ dbuf)
{
    __shared__ float pc[4];
    __shared__ float winv;
    int b = blockIdx.x, l = blockIdx.y, tid = threadIdx.x;
    const int* x0 = xx + (size_t)b * Tsz * S3;
    int c = (x0[tid] != 0) + (x0[tid + 256] != 0);
    for (int off = 32; off; off >>= 1) c += __shfl_xor(c, off, 64);
    if ((tid & 63) == 0) pc[tid >> 6] = (float)c;
    __syncthreads();
    if (tid == 0) {
        float n = pc[0] + pc[1] + pc[2] + pc[3];
        winv = (n > 1.f) ? 1.f / (n - 1.f) : 0.f;
    }
    __syncthreads();
    float inv = winv;
    const float* wl = Wl + l * 16384;
    const float* wr = Wr + l * 16384;
    ushort* dst = dbuf + (size_t)(b * 3 + l) * 32 * 512;
    for (int item = tid; item < 2048; item += 256) {
        int f = item >> 6, lane = item & 63;
        int t = f >> 2, ks = f & 3, ml = lane & 15, q = lane >> 4;
        int n = t * 16 + ml, kb = ks * 32 + q * 8;
        const float4* wlr = (const float4*)(wl + n * 128 + kb);
        const float4* wrr = (const float4*)(wr + n * 128 + kb);
        float4 a0 = wlr[0], a1 = wlr[1];
        float4 r0 = wrr[0], r1 = wrr[1];
        ushort4 o0, o1;
        o0.x = f2bu(r0.x - inv * a0.x); o0.y = f2bu(r0.y - inv * a0.y);
        o0.z = f2bu(r0.z - inv * a0.z); o0.w = f2bu(r0.w - inv * a0.w);
        o1.x = f2bu(r1.x - inv * a1.x); o1.y = f2bu(r1.y - inv * a1.y);
        o1.z = f2bu(r1.z - inv * a1.z); o1.w = f2bu(r1.w - inv * a1.w);
        ushort* dp = dst + (size_t)f * 512 + lane * 8;
        *(ushort4*)dp = o0;
        *(ushort4*)(dp + 4) = o1;
    }
}

// ---------------------------------------------------------------------------
// k_torso: fused init + 3 GNN layers + pool. 1024 threads (16 waves);
// wave wv owns nodes [wv*32, wv*32+32). B-fragments staged 4-at-a-time
// (two transient groups) to keep arch-VGPR peak < 64 and avoid spills.
// ---------------------------------------------------------------------------
__global__ __launch_bounds__(1024) void k_torso(
    const int* __restrict__ xx, const float* __restrict__ ss,
    const float* __restrict__ Win, const float* __restrict__ b_in,
    const ushort* __restrict__ dbuf,
    const float4* __restrict__ WlP, const float* __restrict__ blv,
    const float* __restrict__ lng, const float* __restrict__ lnb,
    float* __restrict__ out)
{
    __shared__ ushort X[512 * 136];
    __shared__ float  mC[512];
    __shared__ float  sred[16 * 128];
    __shared__ float  ssc[128];
    __shared__ float  sbase[128];
    __shared__ float  gln[128], bln[128];
    __shared__ float  scnt[16];
    __shared__ float  invS;

    int b = blockIdx.x, tid = threadIdx.x;
    int wv = tid >> 6, lane = tid & 63;
    int ml = lane & 15, quad = lane >> 4;

    // ================= init =================
    {
        int g = wv, cp = lane;
        int co0 = 2 * cp, co1 = 2 * cp + 1;
        const int* x0 = xx + (size_t)b * Tsz * S3;
        float f4c = ss[b] * (1.0f / 8.0f);
        float a0 = Win[co0*5+0], a1 = Win[co0*5+1], a2 = Win[co0*5+2], a3 = Win[co0*5+3];
        float c0 = Win[co1*5+0], c1 = Win[co1*5+1], c2 = Win[co1*5+2], c3 = Win[co1*5+3];
        float ba = b_in[co0] + f4c * Win[co0*5+4];
        float bc = b_in[co1] + f4c * Win[co1*5+4];
        float sp0 = 0.f, sp1 = 0.f; int cnt = 0;
        for (int node = g; node < S3; node += 16) {
            int f0 = x0[node];
            float m = (f0 != 0) ? 1.f : 0.f;
            float ci = (float)(node >> 6) * (1.f / 7.f);
            float cj = (float)((node >> 3) & 7) * (1.f / 7.f);
            float ck = (float)(node & 7) * (1.f / 7.f);
            float ft = (float)f0 * 0.5f;
            float v0 = ba + ci * a0 + cj * a1 + ck * a2 + ft * a3;
            float v1 = bc + ci * c0 + cj * c1 + ck * c2 + ft * c3;
            ((unsigned*)(X + node * 136))[cp] = fpack2(v0, v1);
            sp0 += v0 * m; sp1 += v1 * m;
            cnt += (f0 != 0);
            if (cp == 0) mC[node] = m;
        }
        sred[g * 128 + co0] = sp0;
        sred[g * 128 + co1] = sp1;
        if (cp == 0) scnt[g] = (float)cnt;
    }
    if (tid < 128) { gln[tid] = lng[tid]; bln[tid] = lnb[tid]; }
    __syncthreads();
    if (tid == 0) {
        float n = 0.f;
#pragma unroll
        for (int g = 0; g < 16; g++) n += scnt[g];
        invS = (n > 1.f) ? 1.f / (n - 1.f) : 0.f;
    }
    __syncthreads();
    if (tid < 128) {
        float s = 0.f;
#pragma unroll
        for (int g = 0; g < 16; g++) s += sred[g * 128 + tid];
        ssc[tid] = s * invS;
    }
    __syncthreads();
    if (tid < 128) {
        float a = blv[tid];
        for (int k4 = 0; k4 < 32; k4++)
            a += dot4(*(const float4*)(ssc + k4 * 4), WlP[k4 * 384 + tid]);
        sbase[tid] = a;
    }
    __syncthreads();

    // ================= 3 SAGE layers =================
    for (int l = 0; l < 3; l++) {
        f32x4 acc[8][2];   // [n-tile][m-tile]
#pragma unroll
        for (int t = 0; t < 8; t++)
#pragma unroll
            for (int m = 0; m < 2; m++) acc[t][m] = (f32x4){0.f, 0.f, 0.f, 0.f};

        const ushort* dL  = dbuf + (size_t)(b * 3 + l) * 32 * 512 + lane * 8;
        const ushort* xr0 = X + (wv * 32 + ml) * 136 + quad * 8;
        const ushort* xr1 = xr0 + 16 * 136;

#pragma unroll
        for (int ks = 0; ks < 4; ks++) {
            short8 a0 = *(const short8*)(xr0 + ks * 32);
            short8 a1 = *(const short8*)(xr1 + ks * 32);
            short8 bg0[4], bg1[4];
#pragma unroll
            for (int t = 0; t < 4; t++)
                bg0[t] = *(const short8*)(dL + (size_t)(t * 4 + ks) * 512);
#pragma unroll
            for (int t = 0; t < 4; t++)
                bg1[t] = *(const short8*)(dL + (size_t)((t + 4) * 4 + ks) * 512);
#pragma unroll
            for (int t = 0; t < 4; t++) {
                acc[t][0] = __builtin_amdgcn_mfma_f32_16x16x32_bf16(a0, bg0[t], acc[t][0], 0, 0, 0);
                acc[t][1] = __builtin_amdgcn_mfma_f32_16x16x32_bf16(a1, bg0[t], acc[t][1], 0, 0, 0);
            }
#pragma unroll
            for (int t = 0; t < 4; t++) {
                acc[t + 4][0] = __builtin_amdgcn_mfma_f32_16x16x32_bf16(a0, bg1[t], acc[t + 4][0], 0, 0, 0);
                acc[t + 4][1] = __builtin_amdgcn_mfma_f32_16x16x32_bf16(a1, bg1[t], acc[t + 4][1], 0, 0, 0);
            }
        }

        // epilogue: relu+base in-place -> LN (shuffle stats) -> bf16 into X
        float bse[8], gg[8], be[8];
#pragma unroll
        for (int t = 0; t < 8; t++) {
            bse[t] = sbase[t * 16 + ml];
            gg[t]  = gln[t * 16 + ml];
            be[t]  = bln[t * 16 + ml];
        }
        float sp[8];
#pragma unroll
        for (int t = 0; t < 8; t++) sp[t] = 0.f;
        bool last = (l == 2);

#pragma unroll
        for (int m = 0; m < 2; m++) {
#pragma unroll
            for (int r = 0; r < 4; r++) {
                int row = wv * 32 + m * 16 + quad * 4 + r;
                float s = 0.f, q = 0.f;
#pragma unroll
                for (int t = 0; t < 8; t++) {
                    float v = fmaxf(acc[t][m][r] + bse[t], 0.f);
                    acc[t][m][r] = v;
                    s += v; q += v * v;
                }
#pragma unroll
                for (int off = 1; off <= 8; off <<= 1) {
                    s += __shfl_xor(s, off, 64);
                    q += __shfl_xor(q, off, 64);
                }
                float mu = s * (1.f / 128.f);
                float rs = rsqrtf(q * (1.f / 128.f) - mu * mu + EPSv);
                float mrow = mC[row];
#pragma unroll
                for (int t = 0; t < 8; t++) {
                    float y = (acc[t][m][r] - mu) * rs * gg[t] + be[t];
                    if (last) y *= mrow;
                    else sp[t] += y * mrow;
                    X[row * 136 + t * 16 + ml] = bfr16(y);
                }
            }
        }

        if (!last) {
#pragma unroll
            for (int t = 0; t < 8; t++) {
                sp[t] += __shfl_xor(sp[t], 16, 64);
                sp[t] += __shfl_xor(sp[t], 32, 64);
            }
            if (quad == 0) {
#pragma unroll
                for (int t = 0; t < 8; t++) sred[wv * 128 + t * 16 + ml] = sp[t];
            }
            __syncthreads();
            if (tid < 128) {
                float s = 0.f;
#pragma unroll
                for (int g = 0; g < 16; g++) s += sred[g * 128 + tid];
                ssc[tid] = s * invS;
            }
            __syncthreads();
            if (tid < 128) {
                float a = blv[(l + 1) * 128 + tid];
                for (int k4 = 0; k4 < 32; k4++)
                    a += dot4(*(const float4*)(ssc + k4 * 4), WlP[k4 * 384 + (l + 1) * 128 + tid]);
                sbase[tid] = a;
            }
            __syncthreads();
        }
    }
    __syncthreads();

    // ================= pool: slice means, 4-channel vectorized =================
    if (tid < 768) {
        int c4 = tid & 31, p = tid >> 5;
        int axis = p >> 3, idx = p & 7;
        float4 sum = {0.f, 0.f, 0.f, 0.f};
        for (int t = 0; t < 64; t++) {
            int node;
            if (axis == 0)      node = idx * 64 + t;
            else if (axis == 1) node = (t >> 3) * 64 + idx * 8 + (t & 7);
            else                node = t * 8 + idx;
            uint2 pk = *(const uint2*)(X + node * 136 + c4 * 4);
            sum.x += ulo(pk.x);
            sum.y += uhi(pk.x);
            sum.z += ulo(pk.y);
            sum.w += uhi(pk.y);
        }
        float4 o;
        o.x = sum.x * (1.f / 64.f); o.y = sum.y * (1.f / 64.f);
        o.z = sum.z * (1.f / 64.f); o.w = sum.w * (1.f / 64.f);
        *(float4*)(out + (size_t)b * 26 * Cc + p * Cc + c4 * 4) = o;
    }
}

// ---------------------------------------------------------------------------
// k_tf3: transformer, bf16 MFMA GEMMs; q/k/v stored bf16 (~50 KB LDS)
// ---------------------------------------------------------------------------
__global__ __launch_bounds__(256) void k_tf3(
    const int* __restrict__ xx, const float* __restrict__ ss,
    const ushort* __restrict__ WactB, const float* __restrict__ bact,
    const ushort* __restrict__ WqkvB, const float* __restrict__ bqkv,
    const ushort* __restrict__ WoB, const float* __restrict__ bo,
    const float* __restrict__ ln1g, const float* __restrict__ ln1b,
    const float* __restrict__ ln2g, const float* __restrict__ ln2b,
    const ushort* __restrict__ W1B, const float* __restrict__ b1v,
    const ushort* __restrict__ W2B, const float* __restrict__ b2v,
    const float* __restrict__ Wsc, const float* __restrict__ bsc,
    float* __restrict__ out)
{
    __shared__ float  As[TT * 132];
    __shared__ ushort Qs[16 * 392];
    __shared__ ushort Ab[16 * 136];
    __shared__ ushort Hs[16 * 136];
    __shared__ ushort Fs[16 * 520];
    __shared__ float  Att[60 * 16];
    __shared__ float  mu_s[TT], rs_s[TT];

    int b = blockIdx.x, tid = threadIdx.x;
    int wv = tid >> 6, lane = tid & 63;
    int ml = lane & 15, quad = lane >> 4;

    const int* xa = xx + (size_t)b * Tsz * S3 + S3;
    for (int f = tid; f < TT * 512; f += 256) {
        int t = f >> 9, s = f & 511;
        Fs[t * 520 + s] = bfr16((float)xa[t * 512 + s]);
    }
    __syncthreads();

    {
        f32x4 acc[2];
#pragma unroll
        for (int i = 0; i < 2; i++) acc[i] = (f32x4){0.f, 0.f, 0.f, 0.f};
        const ushort* ar = Fs + ml * 520 + quad * 8;
        for (int ks = 0; ks < 16; ks++) {
            short8 a = *(const short8*)(ar + ks * 32);
#pragma unroll
            for (int i = 0; i < 2; i++) {
                int n0 = (wv * 2 + i) * 16;
                short8 bfr = *(const short8*)(WactB + (size_t)(n0 + ml) * 512 + quad * 8 + ks * 32);
                acc[i] = __builtin_amdgcn_mfma_f32_16x16x32_bf16(a, bfr, acc[i], 0, 0, 0);
            }
        }
#pragma unroll
        for (int i = 0; i < 2; i++) {
            int col = (wv * 2 + i) * 16 + ml;
            float bb = bact[col];
#pragma unroll
            for (int r = 0; r < 4; r++) {
                int row = quad * 4 + r;
                if (row < TT) As[row * 132 + col] = acc[i][r] + bb;
            }
        }
    }
    __syncthreads();

    for (int l = 0; l < 2; l++) {
        const float* bq  = bqkv + l * 384;
        const float* bol = bo + l * 128;
        const float* g1  = ln1g + l * 128; const float* be1 = ln1b + l * 128;
        const float* g2  = ln2g + l * 128; const float* be2 = ln2b + l * 128;
        const float* b1l = b1v + l * 512;  const float* b2l = b2v + l * 128;

        // LN1
        for (int r = wv; r < TT; r += 4) {
            float2 v = *(const float2*)(As + r * 132 + lane * 2);
            float s = v.x + v.y, q = v.x * v.x + v.y * v.y;
            for (int off = 32; off; off >>= 1) {
                s += __shfl_xor(s, off, 64);
                q += __shfl_xor(q, off, 64);
            }
            if (lane == 0) {
                float mu = s * (1.f / 128.f);
                mu_s[r] = mu;
                rs_s[r] = rsqrtf(q * (1.f / 128.f) - mu * mu + EPSv);
            }
        }
        __syncthreads();
        for (int f = tid; f < TT * 64; f += 256) {
            int t = f >> 6, cp = f & 63;
            float mu = mu_s[t], rs = rs_s[t];
            float x0 = (As[t * 132 + 2 * cp]     - mu) * rs * g1[2 * cp]     + be1[2 * cp];
            float x1 = (As[t * 132 + 2 * cp + 1] - mu) * rs * g1[2 * cp + 1] + be1[2 * cp + 1];
            ((unsigned*)(Ab + t * 136))[cp] = fpack2(x0, x1);
        }
        __syncthreads();

        // qkv (K=128, N=384) -> Qs bf16
        {
            short8 a[4];
            const ushort* ar = Ab + ml * 136 + quad * 8;
#pragma unroll
            for (int ks = 0; ks < 4; ks++) a[ks] = *(const short8*)(ar + ks * 32);
#pragma unroll
            for (int i = 0; i < 6; i++) {
                int n0 = (wv * 6 + i) * 16;
                f32x4 acc = (f32x4){0.f, 0.f, 0.f, 0.f};
                const ushort* wb = WqkvB + (size_t)(l * 384 + n0 + ml) * 128 + quad * 8;
#pragma unroll
                for (int ks = 0; ks < 4; ks++) {
                    short8 bfr = *(const short8*)(wb + ks * 32);
                    acc = __builtin_amdgcn_mfma_f32_16x16x32_bf16(a[ks], bfr, acc, 0, 0, 0);
                }
                int col = n0 + ml;
                float bb = bq[col];
#pragma unroll
                for (int r = 0; r < 4; r++) {
                    int row = quad * 4 + r;
                    if (row < TT) Qs[row * 392 + col] = bfr16(acc[r] + bb);
                }
            }
        }
        __syncthreads();

        // attention scores + softmax
        if (tid < 60) {
            int h = tid / 15, tq = tid % 15;
            const ushort* qp = Qs + tq * 392 + h * 32;
            float sc[TT];
            float mx = -1e30f;
#pragma unroll
            for (int tk = 0; tk < TT; tk++) {
                const ushort* kp = Qs + tk * 392 + 128 + h * 32;
                float d = 0.f;
#pragma unroll
                for (int u = 0; u < 32; u += 4) {
                    uint2 qa = *(const uint2*)(qp + u);
                    uint2 ka = *(const uint2*)(kp + u);
                    d += ulo(qa.x) * ulo(ka.x) + uhi(qa.x) * uhi(ka.x)
                       + ulo(qa.y) * ulo(ka.y) + uhi(qa.y) * uhi(ka.y);
                }
                d *= 0.17677669529663689f;
                sc[tk] = d; mx = fmaxf(mx, d);
            }
            float sum = 0.f;
#pragma unroll
            for (int tk = 0; tk < TT; tk++) { float e = __expf(sc[tk] - mx); sc[tk] = e; sum += e; }
            float r = 1.f / sum;
#pragma unroll
            for (int tk = 0; tk < TT; tk++) Att[tid * 16 + tk] = sc[tk] * r;
        }
        __syncthreads();

        // o = att @ v -> Hs (bf16)
        for (int f = tid; f < TT * 64; f += 256) {
            int t = f >> 6, cp = f & 63;
            int h = cp >> 4;
            const float* ap = Att + (h * 15 + t) * 16;
            const ushort* vp = Qs + 256 + 2 * cp;
            float a0 = 0.f, a1 = 0.f;
#pragma unroll
            for (int tk = 0; tk < TT; tk++) {
                float w = ap[tk];
                unsigned pk = *(const unsigned*)(vp + tk * 392);
                a0 += w * ulo(pk);
                a1 += w * uhi(pk);
            }
            ((unsigned*)(Hs + t * 136))[cp] = fpack2(a0, a1);
        }
        __syncthreads();

        // proj + residual
        {
            short8 a[4];
            const ushort* ar = Hs + ml * 136 + quad * 8;
#pragma unroll
            for (int ks = 0; ks < 4; ks++) a[ks] = *(const short8*)(ar + ks * 32);
#pragma unroll
            for (int i = 0; i < 2; i++) {
                int n0 = (wv * 2 + i) * 16;
                f32x4 acc = (f32x4){0.f, 0.f, 0.f, 0.f};
                const ushort* wb = WoB + (size_t)(l * 128 + n0 + ml) * 128 + quad * 8;
#pragma unroll
                for (int ks = 0; ks < 4; ks++) {
                    short8 bfr = *(const short8*)(wb + ks * 32);
                    acc = __builtin_amdgcn_mfma_f32_16x16x32_bf16(a[ks], bfr, acc, 0, 0, 0);
                }
                int col = n0 + ml;
                float bb = bol[col];
#pragma unroll
                for (int r = 0; r < 4; r++) {
                    int row = quad * 4 + r;
                    if (row < TT) As[row * 132 + col] += acc[r] + bb;
                }
            }
        }
        __syncthreads();

        // LN2
        for (int r = wv; r < TT; r += 4) {
            float2 v = *(const float2*)(As + r * 132 + lane * 2);
            float s = v.x + v.y, q = v.x * v.x + v.y * v.y;
            for (int off = 32; off; off >>= 1) {
                s += __shfl_xor(s, off, 64);
                q += __shfl_xor(q, off, 64);
            }
            if (lane == 0) {
                float mu = s * (1.f / 128.f);
                mu_s[r] = mu;
                rs_s[r] = rsqrtf(q * (1.f / 128.f) - mu * mu + EPSv);
            }
        }
        __syncthreads();
        for (int f = tid; f < TT * 64; f += 256) {
            int t = f >> 6, cp = f & 63;
            float mu = mu_s[t], rs = rs_s[t];
            float x0 = (As[t * 132 + 2 * cp]     - mu) * rs * g2[2 * cp]     + be2[2 * cp];
            float x1 = (As[t * 132 + 2 * cp + 1] - mu) * rs * g2[2 * cp + 1] + be2[2 * cp + 1];
            ((unsigned*)(Ab + t * 136))[cp] = fpack2(x0, x1);
        }
        __syncthreads();

        // ff1 (K=128, N=512)
        {
            short8 a[4];
            const ushort* ar = Ab + ml * 136 + quad * 8;
#pragma unroll
            for (int ks = 0; ks < 4; ks++) a[ks] = *(const short8*)(ar + ks * 32);
#pragma unroll
            for (int i = 0; i < 8; i++) {
                int n0 = (wv * 8 + i) * 16;
                f32x4 acc = (f32x4){0.f, 0.f, 0.f, 0.f};
                const ushort* wb = W1B + (size_t)(l * 512 + n0 + ml) * 128 + quad * 8;
#pragma unroll
                for (int ks = 0; ks < 4; ks++) {
                    short8 bfr = *(const short8*)(wb + ks * 32);
                    acc = __builtin_amdgcn_mfma_f32_16x16x32_bf16(a[ks], bfr, acc, 0, 0, 0);
                }
                int col = n0 + ml;
                float bb = b1l[col];
#pragma unroll
                for (int r = 0; r < 4; r++) {
                    int row = quad * 4 + r;
                    if (row < TT) Fs[row * 520 + col] = bfr16(fmaxf(acc[r] + bb, 0.f));
                }
            }
        }
        __syncthreads();

        // ff2 + residual (K=512, N=128)
        {
            f32x4 acc[2];
#pragma unroll
            for (int i = 0; i < 2; i++) acc[i] = (f32x4){0.f, 0.f, 0.f, 0.f};
            const ushort* ar = Fs + ml * 520 + quad * 8;
            for (int ks = 0; ks < 16; ks++) {
                short8 a = *(const short8*)(ar + ks * 32);
#pragma unroll
                for (int i = 0; i < 2; i++) {
                    int n0 = (wv * 2 + i) * 16;
                    short8 bfr = *(const short8*)(W2B + (size_t)(l * 128 + n0 + ml) * 512 + quad * 8 + ks * 32);
                    acc[i] = __builtin_amdgcn_mfma_f32_16x16x32_bf16(a, bfr, acc[i], 0, 0, 0);
                }
            }
#pragma unroll
            for (int i = 0; i < 2; i++) {
                int col = (wv * 2 + i) * 16 + ml;
                float bb = b2l[col];
#pragma unroll
                for (int r = 0; r < 4; r++) {
                    int row = quad * 4 + r;
                    if (row < TT) As[row * 132 + col] += acc[i][r] + bb;
                }
            }
        }
        __syncthreads();
    }

    if (tid < 128) {
        float s = 0.f;
#pragma unroll
        for (int t = 0; t < TT; t++) s += As[t * 132 + tid];
        out[(size_t)b * 26 * Cc + 24 * Cc + tid] = s * (1.f / 15.f);
    } else if (tid < 256) {
        int co = tid - 128;
        float v = ss[b] * Wsc[co] + bsc[co];
        out[(size_t)b * 26 * Cc + 25 * Cc + co] = fmaxf(v, 0.f);
    }
}

// ---------------------------------------------------------------------------
extern "C" void kernel_launch(void* const* d_in, const int* in_sizes, int n_in,
                              void* d_out, int out_size, void* d_ws, size_t ws_size,
                              hipStream_t stream)
{
    (void)in_sizes; (void)n_in; (void)out_size; (void)ws_size;
    const int*   xx   = (const int*)d_in[0];
    const float* ss   = (const float*)d_in[1];
    const float* Win  = (const float*)d_in[2];
    const float* b_in = (const float*)d_in[3];
    const float* Wl   = (const float*)d_in[4];
    const float* bl   = (const float*)d_in[5];
    const float* Wr   = (const float*)d_in[6];
    const float* lng  = (const float*)d_in[7];
    const float* lnb  = (const float*)d_in[8];
    const float* Wqkv = (const float*)d_in[9];
    const float* bqkv = (const float*)d_in[10];
    const float* Wo   = (const float*)d_in[11];
    const float* bo   = (const float*)d_in[12];
    const float* ln1g = (const float*)d_in[13];
    const float* ln1b = (const float*)d_in[14];
    const float* ln2g = (const float*)d_in[15];
    const float* ln2b = (const float*)d_in[16];
    const float* W1   = (const float*)d_in[17];
    const float* b1   = (const float*)d_in[18];
    const float* W2   = (const float*)d_in[19];
    const float* b2   = (const float*)d_in[20];
    const float* Wact = (const float*)d_in[21];
    const float* bact = (const float*)d_in[22];
    const float* Wsc  = (const float*)d_in[23];
    const float* bsc  = (const float*)d_in[24];
    float* out = (float*)d_out;

    char* ws = (char*)d_ws;
    size_t off = 0;
    float* WlT  = (float*)(ws + off); off += 384 * 128 * 4;
    ushort* dbuf  = (ushort*)(ws + off); off += (size_t)Bsz * 3 * 32 * 512 * 2;
    ushort* WactB = (ushort*)(ws + off); off += 128 * 512 * 2;
    ushort* WqkvB = (ushort*)(ws + off); off += 768 * 128 * 2;
    ushort* WoB   = (ushort*)(ws + off); off += 256 * 128 * 2;
    ushort* W1B   = (ushort*)(ws + off); off += 1024 * 128 * 2;
    ushort* W2B   = (ushort*)(ws + off); off += 256 * 512 * 2;

    k_tpack<<<dim3(4, 12), 256, 0, stream>>>(Wl, WlT, 384, 128);
    k_cvt5<<<448, 256, 0, stream>>>(Wact, Wqkv, Wo, W1, W2, WactB);
    k_dwall<<<dim3(Bsz, 3), 256, 0, stream>>>(xx, Wl, Wr, dbuf);

    k_torso<<<Bsz, 1024, 0, stream>>>(xx, ss, Win, b_in, dbuf,
                                      (const float4*)WlT, bl, lng, lnb, out);

    k_tf3<<<Bsz, 256, 0, stream>>>(xx, ss,
                                   WactB, bact, WqkvB, bqkv, WoB, bo,
                                   ln1g, ln1b, ln2g, ln2b,
                                   W1B, b1, W2B, b2,
                                   Wsc, bsc, out);
}